// Round 1
// baseline (628.488 us; speedup 1.0000x reference)
//
#include <hip/hip_runtime.h>
#include <hip/hip_bf16.h>

typedef unsigned short u16;
typedef __attribute__((ext_vector_type(8))) short bf16x8;   // 8 bf16 = 4 VGPRs
typedef __attribute__((ext_vector_type(4))) float f32x4;

#define B_   2
#define T_   2048
#define DM   2048
#define NH   16
#define DH   128
#define NQKV 6144

__device__ __forceinline__ u16 f2bf(float f) {
  __hip_bfloat16 h = __float2bfloat16(f);
  u16 u; __builtin_memcpy(&u, &h, 2); return u;
}
__device__ __forceinline__ float bf2f(u16 u) {
  __hip_bfloat16 h; __builtin_memcpy(&h, &u, 2); return __bfloat162float(h);
}
// async global->LDS, 16B per lane; lds dest must be wave-uniform base (HW adds lane*16)
__device__ __forceinline__ void gl_lds16(const void* g, void* l) {
  __builtin_amdgcn_global_load_lds(
      (__attribute__((address_space(1))) unsigned int*)g,
      (__attribute__((address_space(3))) unsigned int*)l, 16, 0, 0);
}
__device__ __forceinline__ f32x4 MFMA(bf16x8 a, bf16x8 b, f32x4 c) {
  return __builtin_amdgcn_mfma_f32_16x16x32_bf16(a, b, c, 0, 0, 0);
}

// ---------------- fp32 -> bf16 cast, float4 vectorized ----------------
__global__ __launch_bounds__(256) void cast_kernel(const float* __restrict__ in,
                                                   u16* __restrict__ out, int n4) {
  int i = blockIdx.x * 256 + threadIdx.x;
  if (i >= n4) return;
  float4 v = ((const float4*)in)[i];
  ushort4 o;
  o.x = f2bf(v.x); o.y = f2bf(v.y); o.z = f2bf(v.z); o.w = f2bf(v.w);
  ((ushort4*)out)[i] = o;
}

// ---------------- C = A (MxK) * B^T (NxK), bf16 in, bf16 or f32 out ----
// m97 structure: 128x128 tile, BK=32, 4 waves (2x2 of 64x64), global_load_lds w=16
__global__ __launch_bounds__(256) void gemm_bt(const u16* __restrict__ A,
                                               const u16* __restrict__ Bm,
                                               void* __restrict__ Cp,
                                               int M, int N, int K, int out_f32) {
  __shared__ u16 As[128 * 32];
  __shared__ u16 Bs[128 * 32];
  const int tid  = threadIdx.x;
  const int wave = tid >> 6, lane = tid & 63;
  const int lrow = lane & 15, quad = lane >> 4;
  const long tileM = (long)blockIdx.y * 128, tileN = (long)blockIdx.x * 128;
  const int wm = (wave >> 1) * 64, wn = (wave & 1) * 64;
  // staging: 8 issues of 1KB (16 rows x 64B); wave w does issues {2w, 2w+1}
  const int sRow = wave * 32 + (lane >> 2);
  const int sCol = (lane & 3) * 8;
  const u16* Ag0 = A + (tileM + sRow) * (long)K + sCol;
  const u16* Ag1 = A + (tileM + sRow + 16) * (long)K + sCol;
  const u16* Bg0 = Bm + (tileN + sRow) * (long)K + sCol;
  const u16* Bg1 = Bm + (tileN + sRow + 16) * (long)K + sCol;
  u16* AsW = As + wave * 1024;
  u16* BsW = Bs + wave * 1024;
  const int aOff = (wm + lrow) * 32 + quad * 8;
  const int bOff = (wn + lrow) * 32 + quad * 8;
  f32x4 acc[4][4] = {};
  for (int kt = 0; kt < K; kt += 32) {
    gl_lds16(Ag0 + kt, AsW);
    gl_lds16(Ag1 + kt, AsW + 512);
    gl_lds16(Bg0 + kt, BsW);
    gl_lds16(Bg1 + kt, BsW + 512);
    __syncthreads();
    bf16x8 af[4], bfr[4];
#pragma unroll
    for (int i = 0; i < 4; ++i) af[i]  = *(const bf16x8*)(As + aOff + i * 512);
#pragma unroll
    for (int i = 0; i < 4; ++i) bfr[i] = *(const bf16x8*)(Bs + bOff + i * 512);
#pragma unroll
    for (int mi = 0; mi < 4; ++mi)
#pragma unroll
      for (int ni = 0; ni < 4; ++ni)
        acc[mi][ni] = MFMA(af[mi], bfr[ni], acc[mi][ni]);
    __syncthreads();
  }
  // epilogue: C row = quad*4+r, col = lane&15 (verified m89/m91 mapping)
  const long crow = tileM + wm + quad * 4;
  const long ccol = tileN + wn + lrow;
  if (out_f32) {
    float* C = (float*)Cp;
#pragma unroll
    for (int mi = 0; mi < 4; ++mi)
#pragma unroll
      for (int ni = 0; ni < 4; ++ni)
#pragma unroll
        for (int r = 0; r < 4; ++r)
          C[(crow + mi * 16 + r) * (long)N + (ccol + ni * 16)] = acc[mi][ni][r];
  } else {
    u16* C = (u16*)Cp;
#pragma unroll
    for (int mi = 0; mi < 4; ++mi)
#pragma unroll
      for (int ni = 0; ni < 4; ++ni)
#pragma unroll
        for (int r = 0; r < 4; ++r)
          C[(crow + mi * 16 + r) * (long)N + (ccol + ni * 16)] = f2bf(acc[mi][ni][r]);
  }
}

// ---------------- RoPE + head reorder + V transpose ----------------
// grid (T/64, B*NH); block 256. Writes Q,K as (bh, t, d), V as (bh, d, t).
__global__ __launch_bounds__(256) void rope_reorder(const u16* __restrict__ qkv,
                                                    u16* __restrict__ Q,
                                                    u16* __restrict__ Kd,
                                                    u16* __restrict__ Vt) {
  const int tt = blockIdx.x;           // t-tile of 64
  const int bh = blockIdx.y;
  const int b = bh >> 4, h = bh & 15;
  const int tid = threadIdx.x;
  __shared__ u16 vlds[64 * 129];
  const float qscale = 0.08838834764831845f;  // 1/sqrt(128)
#pragma unroll
  for (int it = 0; it < 16; ++it) {
    int p  = tid + it * 256;           // pair index in 64x64
    int tl = p >> 6;
    int i  = p & 63;                   // rope pair (d = 2i, 2i+1)
    int t  = tt * 64 + tl;
    float freq  = __expf(-9.210340371976184f * (float)i / 64.0f);
    float angle = (float)t * freq;
    float sn, cs;
    sincosf(angle, &sn, &cs);
    const u16* row = qkv + (size_t)(b * T_ + t) * NQKV;
    size_t qo = ((size_t)bh * T_ + t) * DH + 2 * i;
    float q0 = bf2f(row[h * DH + 2 * i]), q1 = bf2f(row[h * DH + 2 * i + 1]);
    Q[qo]     = f2bf((q0 * cs - q1 * sn) * qscale);
    Q[qo + 1] = f2bf((q1 * cs + q0 * sn) * qscale);
    float k0 = bf2f(row[DM + h * DH + 2 * i]), k1 = bf2f(row[DM + h * DH + 2 * i + 1]);
    Kd[qo]     = f2bf(k0 * cs - k1 * sn);
    Kd[qo + 1] = f2bf(k1 * cs + k0 * sn);
  }
  // V: load (t,d) tile coalesced, transpose in LDS, write (d,t) coalesced
#pragma unroll
  for (int it = 0; it < 32; ++it) {
    int idx = tid + it * 256;          // 0..8191
    int tl = idx >> 7, d = idx & 127;
    vlds[tl * 129 + d] =
        qkv[(size_t)(b * T_ + tt * 64 + tl) * NQKV + 2 * DM + h * DH + d];
  }
  __syncthreads();
#pragma unroll
  for (int it = 0; it < 32; ++it) {
    int idx = tid + it * 256;
    int d = idx >> 6, tl = idx & 63;
    Vt[((size_t)bh * DH + d) * T_ + tt * 64 + tl] = vlds[tl * 129 + d];
  }
}

// ---------------- causal flash attention ----------------
// grid (T/64, B*NH); block 256 = 4 waves, each wave owns 16 q-rows.
__global__ __launch_bounds__(256) void attn_flash(const u16* __restrict__ Q,
                                                  const u16* __restrict__ K,
                                                  const u16* __restrict__ Vt,
                                                  u16* __restrict__ AO) {
  __shared__ u16 Kl[64 * 128];   // (key t, d)
  __shared__ u16 Vl[128 * 64];   // (d, key t)  -- transposed V
  __shared__ u16 Pl[4 * 16 * 64];// per-wave P staging (C-layout -> A-layout)
  const int qt = blockIdx.x;
  const int bh = blockIdx.y;
  const int b = bh >> 4, h = bh & 15;
  const int tid = threadIdx.x;
  const int wave = tid >> 6, lane = tid & 63;
  const int lrow = lane & 15, quad = lane >> 4;
  const u16* Qb = Q + (size_t)bh * T_ * DH;
  const u16* Kb = K + (size_t)bh * T_ * DH;
  const u16* Vb = Vt + (size_t)bh * DH * T_;

  // Q fragments in registers (A-layout): 16 rows per wave, Dh=128 -> 4 k-chunks
  bf16x8 qf[4];
  {
    const u16* qrow = Qb + (size_t)(qt * 64 + wave * 16 + lrow) * DH + quad * 8;
#pragma unroll
    for (int kc = 0; kc < 4; ++kc) qf[kc] = *(const bf16x8*)(qrow + kc * 32);
  }
  f32x4 o[8] = {};
  float mrow[4] = {-__builtin_inff(), -__builtin_inff(), -__builtin_inff(), -__builtin_inff()};
  float lsum[4] = {0.f, 0.f, 0.f, 0.f};

  u16* KlW = Kl + wave * 2048;  // 4 issues x 512 elts per wave
  u16* VlW = Vl + wave * 2048;
  const int vd  = lane >> 3;          // Vt staging row-in-issue
  const int vc8 = (lane & 7) * 8;

  for (int j = 0; j <= qt; ++j) {
    // stage K tile (contiguous 16KB) and Vt tile (128 rows x 128B slice)
    const u16* Ksrc = Kb + (size_t)j * 64 * DH + wave * 2048 + lane * 8;
    const u16* Vsrc = Vb + (size_t)(wave * 32 + vd) * T_ + j * 64 + vc8;
#pragma unroll
    for (int i = 0; i < 4; ++i) gl_lds16(Ksrc + i * 512, KlW + i * 512);
#pragma unroll
    for (int i = 0; i < 4; ++i) gl_lds16(Vsrc + (size_t)i * 8 * T_, VlW + i * 512);
    __syncthreads();

    // S = Q K^T   (16 q-rows x 64 keys per wave)
    f32x4 s[4] = {};
#pragma unroll
    for (int kc = 0; kc < 4; ++kc)
#pragma unroll
      for (int ns = 0; ns < 4; ++ns) {
        bf16x8 kf = *(const bf16x8*)(Kl + (ns * 16 + lrow) * 128 + kc * 32 + quad * 8);
        s[ns] = MFMA(qf[kc], kf, s[ns]);
      }
    if (j == qt) {  // causal mask on diagonal tile
#pragma unroll
      for (int ns = 0; ns < 4; ++ns)
#pragma unroll
        for (int r = 0; r < 4; ++r)
          if (ns * 16 + lrow > wave * 16 + quad * 4 + r) s[ns][r] = -__builtin_inff();
    }
    // online softmax: rows live per-quad (C-layout row = quad*4+r, col over 16 lanes)
#pragma unroll
    for (int r = 0; r < 4; ++r) {
      float mx = fmaxf(fmaxf(s[0][r], s[1][r]), fmaxf(s[2][r], s[3][r]));
      mx = fmaxf(mx, __shfl_xor(mx, 1, 16));
      mx = fmaxf(mx, __shfl_xor(mx, 2, 16));
      mx = fmaxf(mx, __shfl_xor(mx, 4, 16));
      mx = fmaxf(mx, __shfl_xor(mx, 8, 16));
      float mnew  = fmaxf(mrow[r], mx);
      float alpha = __expf(mrow[r] - mnew);
      mrow[r] = mnew;
      float rs = 0.f;
#pragma unroll
      for (int ns = 0; ns < 4; ++ns) {
        float p = __expf(s[ns][r] - mnew);
        Pl[wave * 1024 + (quad * 4 + r) * 64 + ns * 16 + lrow] = f2bf(p);
        rs += p;
      }
      rs += __shfl_xor(rs, 1, 16);
      rs += __shfl_xor(rs, 2, 16);
      rs += __shfl_xor(rs, 4, 16);
      rs += __shfl_xor(rs, 8, 16);
      lsum[r] = lsum[r] * alpha + rs;
#pragma unroll
      for (int os = 0; os < 8; ++os) o[os][r] *= alpha;
    }
    __syncthreads();  // P visible; also keeps waves converged

    // O += P V  (P via LDS in A-layout; V already d-major so B-frags contiguous)
#pragma unroll
    for (int kc = 0; kc < 2; ++kc) {
      bf16x8 pf = *(const bf16x8*)(Pl + wave * 1024 + lrow * 64 + kc * 32 + quad * 8);
#pragma unroll
      for (int os = 0; os < 8; ++os) {
        bf16x8 vf = *(const bf16x8*)(Vl + (os * 16 + lrow) * 64 + kc * 32 + quad * 8);
        o[os] = MFMA(pf, vf, o[os]);
      }
    }
    __syncthreads();  // before next tile staging overwrites Kl/Vl
  }
  // normalize and write (b, t, h*128+d) bf16
  float inv[4];
#pragma unroll
  for (int r = 0; r < 4; ++r) inv[r] = 1.0f / lsum[r];
  const size_t rowb = (size_t)b * T_ + qt * 64 + wave * 16 + quad * 4;
#pragma unroll
  for (int r = 0; r < 4; ++r) {
    u16* dst = AO + (rowb + r) * DM + h * DH;
#pragma unroll
    for (int os = 0; os < 8; ++os) dst[os * 16 + lrow] = f2bf(o[os][r] * inv[r]);
  }
}

extern "C" void kernel_launch(void* const* d_in, const int* in_sizes, int n_in,
                              void* d_out, int out_size, void* d_ws, size_t ws_size,
                              hipStream_t stream) {
  const float* x    = (const float*)d_in[0];
  const float* Wqkv = (const float*)d_in[1];
  const float* WO   = (const float*)d_in[2];
  char* ws = (char*)d_ws;
  size_t off = 0;
  u16* xb   = (u16*)(ws + off); off += (size_t)B_ * T_ * DM * 2;        // 16.8MB
  u16* wqb  = (u16*)(ws + off); off += (size_t)NQKV * DM * 2;           // 25.2MB
  u16* wob  = (u16*)(ws + off); off += (size_t)DM * DM * 2;             // 8.4MB
  u16* qkvb = (u16*)(ws + off); off += (size_t)B_ * T_ * NQKV * 2;      // 50.3MB
  u16* Qb   = (u16*)(ws + off); off += (size_t)B_ * NH * T_ * DH * 2;   // 16.8MB
  u16* Kb   = (u16*)(ws + off); off += (size_t)B_ * NH * T_ * DH * 2;
  u16* Vtb  = (u16*)(ws + off); off += (size_t)B_ * NH * T_ * DH * 2;
  u16* AO   = xb;  // alias: xb dead after GEMM1, AO written after

  cast_kernel<<<(B_ * T_ * DM / 4 + 255) / 256, 256, 0, stream>>>(x, xb, B_ * T_ * DM / 4);
  cast_kernel<<<(NQKV * DM / 4 + 255) / 256, 256, 0, stream>>>(Wqkv, wqb, NQKV * DM / 4);
  cast_kernel<<<(DM * DM / 4 + 255) / 256, 256, 0, stream>>>(WO, wob, DM * DM / 4);

  gemm_bt<<<dim3(NQKV / 128, B_ * T_ / 128), 256, 0, stream>>>(
      xb, wqb, qkvb, B_ * T_, NQKV, DM, 0);

  rope_reorder<<<dim3(T_ / 64, B_ * NH), 256, 0, stream>>>(qkvb, Qb, Kb, Vtb);

  attn_flash<<<dim3(T_ / 64, B_ * NH), 256, 0, stream>>>(Qb, Kb, Vtb, AO);

  gemm_bt<<<dim3(DM / 128, B_ * T_ / 128), 256, 0, stream>>>(
      AO, wob, d_out, B_ * T_, DM, DM, 1);
}

// Round 2
// 502.390 us; speedup vs baseline: 1.2510x; 1.2510x over previous
//
#include <hip/hip_runtime.h>
#include <hip/hip_bf16.h>

typedef unsigned short u16;
typedef __attribute__((ext_vector_type(8))) short bf16x8;   // 8 bf16 = 4 VGPRs
typedef __attribute__((ext_vector_type(4))) float f32x4;

#define B_   2
#define T_   2048
#define DM   2048
#define NH   16
#define DH   128
#define NQKV 6144

__device__ __forceinline__ u16 f2bf(float f) {
  __hip_bfloat16 h = __float2bfloat16(f);
  u16 u; __builtin_memcpy(&u, &h, 2); return u;
}
__device__ __forceinline__ float bf2f(u16 u) {
  __hip_bfloat16 h; __builtin_memcpy(&h, &u, 2); return __bfloat162float(h);
}
// async global->LDS, 16B per lane; lds dest must be wave-uniform base (HW adds lane*16)
__device__ __forceinline__ void gl_lds16(const void* g, void* l) {
  __builtin_amdgcn_global_load_lds(
      (__attribute__((address_space(1))) unsigned int*)g,
      (__attribute__((address_space(3))) unsigned int*)l, 16, 0, 0);
}
__device__ __forceinline__ f32x4 MFMA(bf16x8 a, bf16x8 b, f32x4 c) {
  return __builtin_amdgcn_mfma_f32_16x16x32_bf16(a, b, c, 0, 0, 0);
}

// ---------------- fp32 -> bf16 cast, float4 vectorized ----------------
__global__ __launch_bounds__(256) void cast_kernel(const float* __restrict__ in,
                                                   u16* __restrict__ out, int n4) {
  int i = blockIdx.x * 256 + threadIdx.x;
  if (i >= n4) return;
  float4 v = ((const float4*)in)[i];
  ushort4 o;
  o.x = f2bf(v.x); o.y = f2bf(v.y); o.z = f2bf(v.z); o.w = f2bf(v.w);
  ((ushort4*)out)[i] = o;
}

// ---------------- C = A (MxK) * B^T (NxK), bf16 in, bf16 or f32 out ----
// m97 structure: 128x128 tile, BK=32, 4 waves (2x2 of 64x64), global_load_lds w=16
__global__ __launch_bounds__(256) void gemm_bt(const u16* __restrict__ A,
                                               const u16* __restrict__ Bm,
                                               void* __restrict__ Cp,
                                               int M, int N, int K, int out_f32) {
  __shared__ u16 As[128 * 32];
  __shared__ u16 Bs[128 * 32];
  const int tid  = threadIdx.x;
  const int wave = tid >> 6, lane = tid & 63;
  const int lrow = lane & 15, quad = lane >> 4;
  const long tileM = (long)blockIdx.y * 128, tileN = (long)blockIdx.x * 128;
  const int wm = (wave >> 1) * 64, wn = (wave & 1) * 64;
  // staging: 8 issues of 1KB (16 rows x 64B); wave w does issues {2w, 2w+1}
  const int sRow = wave * 32 + (lane >> 2);
  const int sCol = (lane & 3) * 8;
  const u16* Ag0 = A + (tileM + sRow) * (long)K + sCol;
  const u16* Ag1 = A + (tileM + sRow + 16) * (long)K + sCol;
  const u16* Bg0 = Bm + (tileN + sRow) * (long)K + sCol;
  const u16* Bg1 = Bm + (tileN + sRow + 16) * (long)K + sCol;
  u16* AsW = As + wave * 1024;
  u16* BsW = Bs + wave * 1024;
  const int aOff = (wm + lrow) * 32 + quad * 8;
  const int bOff = (wn + lrow) * 32 + quad * 8;
  f32x4 acc[4][4] = {};
  for (int kt = 0; kt < K; kt += 32) {
    gl_lds16(Ag0 + kt, AsW);
    gl_lds16(Ag1 + kt, AsW + 512);
    gl_lds16(Bg0 + kt, BsW);
    gl_lds16(Bg1 + kt, BsW + 512);
    __syncthreads();
    bf16x8 af[4], bfr[4];
#pragma unroll
    for (int i = 0; i < 4; ++i) af[i]  = *(const bf16x8*)(As + aOff + i * 512);
#pragma unroll
    for (int i = 0; i < 4; ++i) bfr[i] = *(const bf16x8*)(Bs + bOff + i * 512);
#pragma unroll
    for (int mi = 0; mi < 4; ++mi)
#pragma unroll
      for (int ni = 0; ni < 4; ++ni)
        acc[mi][ni] = MFMA(af[mi], bfr[ni], acc[mi][ni]);
    __syncthreads();
  }
  // epilogue: C row = quad*4+r, col = lane&15 (verified m89/m91 mapping)
  const long crow = tileM + wm + quad * 4;
  const long ccol = tileN + wn + lrow;
  if (out_f32) {
    float* C = (float*)Cp;
#pragma unroll
    for (int mi = 0; mi < 4; ++mi)
#pragma unroll
      for (int ni = 0; ni < 4; ++ni)
#pragma unroll
        for (int r = 0; r < 4; ++r)
          C[(crow + mi * 16 + r) * (long)N + (ccol + ni * 16)] = acc[mi][ni][r];
  } else {
    u16* C = (u16*)Cp;
#pragma unroll
    for (int mi = 0; mi < 4; ++mi)
#pragma unroll
      for (int ni = 0; ni < 4; ++ni)
#pragma unroll
        for (int r = 0; r < 4; ++r)
          C[(crow + mi * 16 + r) * (long)N + (ccol + ni * 16)] = f2bf(acc[mi][ni][r]);
  }
}

// ---------------- RoPE + head reorder + V transpose ----------------
// grid (T/64, B*NH); block 256. Writes Q,K as (bh, t, d), V as (bh, d, t).
__global__ __launch_bounds__(256) void rope_reorder(const u16* __restrict__ qkv,
                                                    u16* __restrict__ Q,
                                                    u16* __restrict__ Kd,
                                                    u16* __restrict__ Vt) {
  const int tt = blockIdx.x;           // t-tile of 64
  const int bh = blockIdx.y;
  const int b = bh >> 4, h = bh & 15;
  const int tid = threadIdx.x;
  __shared__ u16 vlds[64 * 129];
  const float qscale = 0.08838834764831845f;  // 1/sqrt(128)
#pragma unroll
  for (int it = 0; it < 16; ++it) {
    int p  = tid + it * 256;           // pair index in 64x64
    int tl = p >> 6;
    int i  = p & 63;                   // rope pair (d = 2i, 2i+1)
    int t  = tt * 64 + tl;
    float freq  = __expf(-9.210340371976184f * (float)i / 64.0f);
    float angle = (float)t * freq;
    float sn, cs;
    sincosf(angle, &sn, &cs);
    const u16* row = qkv + (size_t)(b * T_ + t) * NQKV;
    size_t qo = ((size_t)bh * T_ + t) * DH + 2 * i;
    float q0 = bf2f(row[h * DH + 2 * i]), q1 = bf2f(row[h * DH + 2 * i + 1]);
    Q[qo]     = f2bf((q0 * cs - q1 * sn) * qscale);
    Q[qo + 1] = f2bf((q1 * cs + q0 * sn) * qscale);
    float k0 = bf2f(row[DM + h * DH + 2 * i]), k1 = bf2f(row[DM + h * DH + 2 * i + 1]);
    Kd[qo]     = f2bf(k0 * cs - k1 * sn);
    Kd[qo + 1] = f2bf(k1 * cs + k0 * sn);
  }
  // V: load (t,d) tile coalesced, transpose in LDS, write (d,t) coalesced
#pragma unroll
  for (int it = 0; it < 32; ++it) {
    int idx = tid + it * 256;          // 0..8191
    int tl = idx >> 7, d = idx & 127;
    vlds[tl * 129 + d] =
        qkv[(size_t)(b * T_ + tt * 64 + tl) * NQKV + 2 * DM + h * DH + d];
  }
  __syncthreads();
#pragma unroll
  for (int it = 0; it < 32; ++it) {
    int idx = tid + it * 256;
    int d = idx >> 6, tl = idx & 63;
    Vt[((size_t)bh * DH + d) * T_ + tt * 64 + tl] = vlds[tl * 129 + d];
  }
}

// ---------------- causal flash attention ----------------
// grid (T/64, B*NH); block 256 = 4 waves, each wave owns 16 q-rows.
// LDS layouts are XOR-swizzled at 16B-chunk granularity to kill bank
// conflicts: chunk c of row r lives at slot c ^ (r % nchunks). Staging via
// global_load_lds applies the swizzle on the *global* source address.
__global__ __launch_bounds__(256) void attn_flash(const u16* __restrict__ Q,
                                                  const u16* __restrict__ K,
                                                  const u16* __restrict__ Vt,
                                                  u16* __restrict__ AO) {
  __shared__ u16 Kl[64 * 128];   // (key t, d), 16 chunks/row, swizzled
  __shared__ u16 Vl[128 * 64];   // (d, key t), 8 chunks/row, swizzled
  __shared__ u16 Pl[4 * 16 * 64];// per-wave P staging, 8 chunks/row, swizzled
  const int qt = gridDim.x - 1 - blockIdx.x;  // heavy (long-loop) blocks first
  const int bh = blockIdx.y;
  const int b = bh >> 4, h = bh & 15;
  const int tid = threadIdx.x;
  const int wave = tid >> 6, lane = tid & 63;
  const int lrow = lane & 15, quad = lane >> 4;
  const u16* Qb = Q + (size_t)bh * T_ * DH;
  const u16* Kb = K + (size_t)bh * T_ * DH;
  const u16* Vb = Vt + (size_t)bh * DH * T_;

  // Q fragments in registers (A-layout): 16 rows per wave, Dh=128 -> 4 k-chunks
  bf16x8 qf[4];
  {
    const u16* qrow = Qb + (size_t)(qt * 64 + wave * 16 + lrow) * DH + quad * 8;
#pragma unroll
    for (int kc = 0; kc < 4; ++kc) qf[kc] = *(const bf16x8*)(qrow + kc * 32);
  }
  f32x4 o[8] = {};
  float mrow[4] = {-__builtin_inff(), -__builtin_inff(), -__builtin_inff(), -__builtin_inff()};
  float lsum[4] = {0.f, 0.f, 0.f, 0.f};

  u16* KlW = Kl + wave * 2048;  // wave stages rows [wave*16, wave*16+16)
  u16* VlW = Vl + wave * 2048;  // wave stages d-rows [wave*32, wave*32+32)
  // K staging: row-in-issue = lane>>4, slot = lane&15, source chunk = slot^(row&15)
  const int kRowIn = lane >> 4;                 // 0..3
  const int kChunk = (lane & 15) ^ kRowIn;      // (row&15) = i*4 + kRowIn; fold i later
  // V staging: row-in-issue = lane>>3, slot = lane&7, source chunk = slot^(row&7)
  const int vRowIn = lane >> 3;                 // 0..7
  const int vChunk = (lane & 7) ^ vRowIn;       // (row&7) = vRowIn (i*8 wraps)

  for (int j = 0; j <= qt; ++j) {
    // stage K tile (64 rows x 256B) and Vt tile (128 d-rows x 128B slice)
#pragma unroll
    for (int i = 0; i < 4; ++i) {
      int krow = wave * 16 + i * 4 + kRowIn;
      // source chunk = (lane&15) ^ ((i*4 + kRowIn)&15); i*4 XOR folds since kRowIn<4
      int kch = (lane & 15) ^ (i * 4 + kRowIn);
      gl_lds16(Kb + (size_t)(j * 64 + krow) * DH + kch * 8, KlW + i * 512);
    }
#pragma unroll
    for (int i = 0; i < 4; ++i) {
      int vd = wave * 32 + i * 8 + vRowIn;
      gl_lds16(Vb + (size_t)vd * T_ + j * 64 + vChunk * 8, VlW + i * 512);
    }
    __syncthreads();

    // S = Q K^T   (16 q-rows x 64 keys per wave)
    f32x4 s[4] = {};
#pragma unroll
    for (int kc = 0; kc < 4; ++kc)
#pragma unroll
      for (int ns = 0; ns < 4; ++ns) {
        bf16x8 kf = *(const bf16x8*)(Kl + (ns * 16 + lrow) * 128 +
                                     (((kc * 4 + quad) ^ lrow) * 8));
        s[ns] = MFMA(qf[kc], kf, s[ns]);
      }
    if (j == qt) {  // causal mask on diagonal tile
#pragma unroll
      for (int ns = 0; ns < 4; ++ns)
#pragma unroll
        for (int r = 0; r < 4; ++r)
          if (ns * 16 + lrow > wave * 16 + quad * 4 + r) s[ns][r] = -__builtin_inff();
    }
    // online softmax: rows live per-quad (C-layout row = quad*4+r, col over 16 lanes)
#pragma unroll
    for (int r = 0; r < 4; ++r) {
      float mx = fmaxf(fmaxf(s[0][r], s[1][r]), fmaxf(s[2][r], s[3][r]));
      mx = fmaxf(mx, __shfl_xor(mx, 1, 16));
      mx = fmaxf(mx, __shfl_xor(mx, 2, 16));
      mx = fmaxf(mx, __shfl_xor(mx, 4, 16));
      mx = fmaxf(mx, __shfl_xor(mx, 8, 16));
      float mnew  = fmaxf(mrow[r], mx);
      float alpha = __expf(mrow[r] - mnew);
      mrow[r] = mnew;
      const int prow = quad * 4 + r;
      float rs = 0.f;
#pragma unroll
      for (int ns = 0; ns < 4; ++ns) {
        float p = __expf(s[ns][r] - mnew);
        // P[prow][col], col = ns*16+lrow, swizzled: slot = (col>>3) ^ (prow&7)
        Pl[wave * 1024 + prow * 64 +
           (((ns * 2 + (lrow >> 3)) ^ (prow & 7)) * 8) + (lrow & 7)] = f2bf(p);
        rs += p;
      }
      rs += __shfl_xor(rs, 1, 16);
      rs += __shfl_xor(rs, 2, 16);
      rs += __shfl_xor(rs, 4, 16);
      rs += __shfl_xor(rs, 8, 16);
      lsum[r] = lsum[r] * alpha + rs;
#pragma unroll
      for (int os = 0; os < 8; ++os) o[os][r] *= alpha;
    }
    // NO barrier here: Pl is per-wave (same-wave cross-lane LDS write->read is
    // ordered by the compiler's lgkmcnt wait).

    // O += P V  (P via LDS in A-layout; V d-major so B-frags contiguous)
#pragma unroll
    for (int kc = 0; kc < 2; ++kc) {
      bf16x8 pf = *(const bf16x8*)(Pl + wave * 1024 + lrow * 64 +
                                   (((kc * 4 + quad) ^ (lrow & 7)) * 8));
#pragma unroll
      for (int os = 0; os < 8; ++os) {
        bf16x8 vf = *(const bf16x8*)(Vl + (os * 16 + lrow) * 64 +
                                     (((kc * 4 + quad) ^ (lrow & 7)) * 8));
        o[os] = MFMA(pf, vf, o[os]);
      }
    }
    __syncthreads();  // before next tile staging overwrites Kl/Vl
  }
  // normalize and write (b, t, h*128+d) bf16
  float inv[4];
#pragma unroll
  for (int r = 0; r < 4; ++r) inv[r] = 1.0f / lsum[r];
  const size_t rowb = (size_t)b * T_ + qt * 64 + wave * 16 + quad * 4;
#pragma unroll
  for (int r = 0; r < 4; ++r) {
    u16* dst = AO + (rowb + r) * DM + h * DH;
#pragma unroll
    for (int os = 0; os < 8; ++os) dst[os * 16 + lrow] = f2bf(o[os][r] * inv[r]);
  }
}

extern "C" void kernel_launch(void* const* d_in, const int* in_sizes, int n_in,
                              void* d_out, int out_size, void* d_ws, size_t ws_size,
                              hipStream_t stream) {
  const float* x    = (const float*)d_in[0];
  const float* Wqkv = (const float*)d_in[1];
  const float* WO   = (const float*)d_in[2];
  char* ws = (char*)d_ws;
  size_t off = 0;
  u16* xb   = (u16*)(ws + off); off += (size_t)B_ * T_ * DM * 2;        // 16.8MB
  u16* wqb  = (u16*)(ws + off); off += (size_t)NQKV * DM * 2;           // 25.2MB
  u16* wob  = (u16*)(ws + off); off += (size_t)DM * DM * 2;             // 8.4MB
  u16* qkvb = (u16*)(ws + off); off += (size_t)B_ * T_ * NQKV * 2;      // 50.3MB
  u16* Qb   = (u16*)(ws + off); off += (size_t)B_ * NH * T_ * DH * 2;   // 16.8MB
  u16* Kb   = (u16*)(ws + off); off += (size_t)B_ * NH * T_ * DH * 2;
  u16* Vtb  = (u16*)(ws + off); off += (size_t)B_ * NH * T_ * DH * 2;
  u16* AO   = xb;  // alias: xb dead after GEMM1, AO written after

  cast_kernel<<<(B_ * T_ * DM / 4 + 255) / 256, 256, 0, stream>>>(x, xb, B_ * T_ * DM / 4);
  cast_kernel<<<(NQKV * DM / 4 + 255) / 256, 256, 0, stream>>>(Wqkv, wqb, NQKV * DM / 4);
  cast_kernel<<<(DM * DM / 4 + 255) / 256, 256, 0, stream>>>(WO, wob, DM * DM / 4);

  gemm_bt<<<dim3(NQKV / 128, B_ * T_ / 128), 256, 0, stream>>>(
      xb, wqb, qkvb, B_ * T_, NQKV, DM, 0);

  rope_reorder<<<dim3(T_ / 64, B_ * NH), 256, 0, stream>>>(qkvb, Qb, Kb, Vtb);

  attn_flash<<<dim3(T_ / 64, B_ * NH), 256, 0, stream>>>(Qb, Kb, Vtb, AO);

  gemm_bt<<<dim3(DM / 128, B_ * T_ / 128), 256, 0, stream>>>(
      AO, wob, d_out, B_ * T_, DM, DM, 1);
}